// Round 3
// baseline (104.304 us; speedup 1.0000x reference)
//
#include <hip/hip_runtime.h>
#include <hip/hip_bf16.h>

typedef float f32x4 __attribute__((ext_vector_type(4)));
typedef int   i32x4 __attribute__((ext_vector_type(4)));
typedef int   i32x8 __attribute__((ext_vector_type(8)));

#define NC 4096
#define ND 1024
#define EPSF 1e-10f
#define NT 8        // K-tiles of BK=128 (fp8)
#define SCALE1 127  // E8M0 exponent byte for 2^0

// ---------------- class mask (LDS bitmap, no atomics) + zero accum ----------------
__global__ void mask_kernel(const int* __restrict__ ann, int n, float* __restrict__ counts) {
  __shared__ unsigned char mark[NC];
  int tid = threadIdx.x;
  for (int i = tid; i < NC; i += 256) mark[i] = 0;
  __syncthreads();
  for (int t = tid; t < n; t += 256) {
    int idx = ann[t * 5 + 4];
    if (idx >= 0 && idx < NC) mark[idx] = 1;  // benign race: all write 1
  }
  __syncthreads();
  for (int i = tid; i < NC + 8; i += 256) counts[i] = (i < NC) ? (float)mark[i] : 0.f;
}

// ---------------- fp32 -> fp8 e4m3 convert + row norms/sums ----------------
__global__ void convert_kernel(const float* __restrict__ F, const float* __restrict__ P,
                               unsigned char* __restrict__ Fb, unsigned char* __restrict__ Pb,
                               float* __restrict__ f2, float* __restrict__ p2,
                               float* __restrict__ psum) {
  int bid = blockIdx.x;
  bool isP = bid >= NC;
  int row = isP ? bid - NC : bid;
  const float* src = (isP ? P : F) + (size_t)row * ND;
  unsigned char* dst = (isP ? Pb : Fb) + (size_t)row * ND;
  int tid = threadIdx.x;
  float4 v = *reinterpret_cast<const float4*>(src + tid * 4);
  int pk = __builtin_amdgcn_cvt_pk_fp8_f32(v.x, v.y, 0, false);   // bytes 0,1
  pk = __builtin_amdgcn_cvt_pk_fp8_f32(v.z, v.w, pk, true);       // bytes 2,3
  *reinterpret_cast<int*>(dst + tid * 4) = pk;
  float sq = v.x * v.x + v.y * v.y + v.z * v.z + v.w * v.w;
  float sm = v.x + v.y + v.z + v.w;
  #pragma unroll
  for (int off = 32; off; off >>= 1) {
    sq += __shfl_down(sq, off);
    sm += __shfl_down(sm, off);
  }
  __shared__ float rs[4], rm[4];
  int wid = tid >> 6, lane = tid & 63;
  if (lane == 0) { rs[wid] = sq; rm[wid] = sm; }
  __syncthreads();
  if (tid == 0) {
    float tsq = rs[0] + rs[1] + rs[2] + rs[3];
    float tsm = rm[0] + rm[1] + rm[2] + rm[3];
    if (isP) { p2[row] = tsq; psum[row] = tsm; }
    else     { f2[row] = tsq; }
  }
}

// ---------------- fused 256x256 8-phase MX-fp8 GEMM + loss reduction ----------------
#define GLDS(gsrc, ldst)                                                     \
  __builtin_amdgcn_global_load_lds(                                          \
      (__attribute__((address_space(1))) void*)(void*)(gsrc),                \
      (__attribute__((address_space(3))) void*)(void*)(ldst), 16, 0, 0)

#define FENCE() asm volatile("" ::: "memory")
#define BAR()  do { FENCE(); __builtin_amdgcn_s_barrier(); FENCE(); } while (0)
#define VMCNT4() asm volatile("s_waitcnt vmcnt(4)" ::: "memory")

// Stage half-tile h (0=A0,1=A1,2=B0,3=B1) of K-tile kt into dbuf d.
// Half-tile = 128 rows x 128 B (fp8). Linear LDS dest, inverse-swizzled
// global source; ds_read applies the matching XOR (rule 21).
#define STAGE(d, h, kt)                                                       \
  do {                                                                        \
    const unsigned char* _m = ((h) < 2) ? Fb : Pb;                            \
    size_t _rb = (((h) < 2) ? arow : brow) + (size_t)(((h) & 1) * 128) * ND;  \
    _Pragma("unroll")                                                         \
    for (int _c = 0; _c < 2; ++_c)                                            \
      GLDS(_m + _rb + (size_t)srow[_c] * ND + (size_t)(kt) * 128 + scol[_c],  \
           &lds[d][h][ldso[_c]]);                                             \
  } while (0)

#define LDA(DB, QM)                                                           \
  do {                                                                        \
    const unsigned char* _b = &lds[DB][wr][0];                                \
    _Pragma("unroll")                                                         \
    for (int _mm = 0; _mm < 4; ++_mm) {                                       \
      int _r = (QM) * 64 + _mm * 16 + lo;                                     \
      int _x = (_r & 7) << 4;                                                 \
      i32x4 _l0 = *(const i32x4*)(_b + _r * 128 + ((hi * 32) ^ _x));          \
      i32x4 _l1 = *(const i32x4*)(_b + _r * 128 + ((hi * 32 + 16) ^ _x));     \
      av[_mm][0] = _l0[0]; av[_mm][1] = _l0[1];                               \
      av[_mm][2] = _l0[2]; av[_mm][3] = _l0[3];                               \
      av[_mm][4] = _l1[0]; av[_mm][5] = _l1[1];                               \
      av[_mm][6] = _l1[2]; av[_mm][7] = _l1[3];                               \
    }                                                                         \
  } while (0)

#define LDB(DB, QN, BV)                                                       \
  do {                                                                        \
    const unsigned char* _b = &lds[DB][2 + (wc >> 1)][0];                     \
    _Pragma("unroll")                                                         \
    for (int _nn = 0; _nn < 2; ++_nn) {                                       \
      int _r = (wc & 1) * 64 + (QN) * 32 + _nn * 16 + lo;                     \
      int _x = (_r & 7) << 4;                                                 \
      i32x4 _l0 = *(const i32x4*)(_b + _r * 128 + ((hi * 32) ^ _x));          \
      i32x4 _l1 = *(const i32x4*)(_b + _r * 128 + ((hi * 32 + 16) ^ _x));     \
      BV[_nn][0] = _l0[0]; BV[_nn][1] = _l0[1];                               \
      BV[_nn][2] = _l0[2]; BV[_nn][3] = _l0[3];                               \
      BV[_nn][4] = _l1[0]; BV[_nn][5] = _l1[1];                               \
      BV[_nn][6] = _l1[2]; BV[_nn][7] = _l1[3];                               \
    }                                                                         \
  } while (0)

#define MMA(QM, QN, BV)                                                       \
  do {                                                                        \
    __builtin_amdgcn_s_setprio(1);                                            \
    _Pragma("unroll")                                                         \
    for (int _mm = 0; _mm < 4; ++_mm)                                         \
      _Pragma("unroll")                                                       \
      for (int _nn = 0; _nn < 2; ++_nn)                                       \
        acc[(QM) * 4 + _mm][(QN) * 2 + _nn] =                                 \
            __builtin_amdgcn_mfma_scale_f32_16x16x128_f8f6f4(                 \
                av[_mm], BV[_nn], acc[(QM) * 4 + _mm][(QN) * 2 + _nn],        \
                0 /*A=fp8*/, 0 /*B=fp8*/, 0, SCALE1, 0, SCALE1);              \
    __builtin_amdgcn_s_setprio(0);                                            \
  } while (0)

__global__ __launch_bounds__(512, 2)
void gemm_loss_kernel(const unsigned char* __restrict__ Fb,
                      const unsigned char* __restrict__ Pb,
                      const float* __restrict__ f2, const float* __restrict__ p2,
                      const float* __restrict__ counts, const float* __restrict__ psum,
                      float* accum) {
  // [dbuf][half: A0,A1,B0,B1][128 rows x 128 B] => 128 KiB total
  __shared__ __attribute__((aligned(16))) unsigned char lds[2][4][16384];
  __shared__ float redI[8], redE[8];

  // XCD-bijective swizzle: 256 wgs, 8 XCDs, 32 contiguous tiles each
  const int wg = (blockIdx.x & 7) * 32 + (blockIdx.x >> 3);
  const int bi = wg >> 4, bj = wg & 15;

  const int tid = threadIdx.x;
  const int lane = tid & 63, wid = tid >> 6;
  const int wr = wid >> 2, wc = wid & 3;  // 2 (M) x 4 (N) wave grid; 128x64 per wave
  const int lo = lane & 15, hi = lane >> 4;

  // staging chunk geometry: 1024 chunks of 16 B per half-tile, 2 per thread
  int srow[2], scol[2], ldso[2];
  #pragma unroll
  for (int c = 0; c < 2; ++c) {
    int idx = c * 512 + tid;
    srow[c] = idx >> 3;                       // row 0..127
    scol[c] = ((idx & 7) ^ (srow[c] & 7)) * 16;  // byte offset in 128-B row
    ldso[c] = idx * 16;
  }
  const size_t arow = (size_t)(bi * 256) * ND;
  const size_t brow = (size_t)(bj * 256) * ND;

  i32x8 av[4], bv0[2], bv1[2];
  f32x4 acc[8][4];
  f32x4 zero = {0.f, 0.f, 0.f, 0.f};
  #pragma unroll
  for (int m = 0; m < 8; ++m)
    #pragma unroll
    for (int n = 0; n < 4; ++n) acc[m][n] = zero;

  // Prologue: K-tile 0 fully into dbuf0; B-halves of K-tile 1 into dbuf1.
  STAGE(0, 0, 0); STAGE(0, 1, 0); STAGE(0, 2, 0); STAGE(0, 3, 0);
  STAGE(1, 2, 1); STAGE(1, 3, 1);
  VMCNT4();  // dbuf0 landed; dbuf1's 4 B-loads may stay in flight
  BAR();

  // 4 iterations, 2 K-tiles each (NT=8). Even K-tile in dbuf0 (P1-P4),
  // odd in dbuf1 (P5-P8). A-halves consumed by P3, B-halves by P2.
  #pragma unroll 1
  for (int it = 0; it < NT / 2; ++it) {
    const int k1 = 2 * it + 1, kn0 = 2 * it + 2, kn1 = 2 * it + 3;
    // P1
    LDA(0, 0); LDB(0, 0, bv0);
    STAGE(1, 0, k1);                       // A0 of k1
    BAR(); MMA(0, 0, bv0); BAR();
    // P2
    LDB(0, 1, bv1);
    STAGE(1, 1, k1);                       // A1 of k1
    BAR(); MMA(0, 1, bv1); BAR();
    // P3
    LDA(0, 1);
    if (kn0 < NT) STAGE(0, 2, kn0);        // B0 of k0+2
    BAR(); MMA(1, 0, bv0); BAR();
    // P4
    if (kn0 < NT) STAGE(0, 3, kn0);        // B1 of k0+2
    VMCNT4();                              // dbuf1 (k1) fully landed
    BAR(); MMA(1, 1, bv1); BAR();
    // P5
    LDA(1, 0); LDB(1, 0, bv0);
    if (kn0 < NT) STAGE(0, 0, kn0);        // A0 of k0+2
    BAR(); MMA(0, 0, bv0); BAR();
    // P6
    LDB(1, 1, bv1);
    if (kn0 < NT) STAGE(0, 1, kn0);        // A1 of k0+2
    BAR(); MMA(0, 1, bv1); BAR();
    // P7
    LDA(1, 1);
    if (kn1 < NT) STAGE(1, 2, kn1);        // B0 of k1+2
    BAR(); MMA(1, 0, bv0); BAR();
    // P8
    if (kn1 < NT) STAGE(1, 3, kn1);        // B1 of k1+2
    VMCNT4();                              // dbuf0 (k0+2) fully landed
    BAR(); MMA(1, 1, bv1); BAR();
  }

  // Epilogue: per-element msd -> intra (diag) / inter (off-diag) partials.
  // C/D layout (shape-determined, dtype-independent): col=lane&15, row=(lane>>4)*4+reg.
  float intra_l = 0.f, inter_l = 0.f;
  const int gi0 = bi * 256 + wr * 128 + hi * 4;
  const int gj0 = bj * 256 + wc * 64 + lo;
  float f2i[32];
  int mi[32];
  #pragma unroll
  for (int m = 0; m < 8; ++m)
    #pragma unroll
    for (int r = 0; r < 4; ++r) {
      int gi = gi0 + m * 16 + r;
      f2i[m * 4 + r] = f2[gi];
      mi[m * 4 + r] = counts[gi] > 0.f;
    }
  #pragma unroll
  for (int n = 0; n < 4; ++n) {
    int gj = gj0 + n * 16;
    float p2j = p2[gj];
    bool mj = psum[gj] != 0.f;
    if (mj) {
      #pragma unroll
      for (int m = 0; m < 8; ++m) {
        #pragma unroll
        for (int r = 0; r < 4; ++r) {
          if (!mi[m * 4 + r]) continue;
          int gi = gi0 + m * 16 + r;
          float cij = acc[m][n][r];
          float msd = fmaxf(f2i[m * 4 + r] + p2j - 2.f * cij, 0.f) * (1.f / 1024.f);
          if (gi == gj) {
            intra_l += msd;                 // diagonal: intra
          } else if (msd < 1.0f) {          // inter term nonzero only if sqrt(msd)<1
            float s = sqrtf(fmaxf(msd, 1e-12f));
            float e = 1.f - s;
            float e2 = e * e;
            inter_l += e2 * e2;             // (e/M)^2 * max(e,0)^2, M=1
          }
        }
      }
    }
  }
  #pragma unroll
  for (int off = 32; off; off >>= 1) {
    intra_l += __shfl_down(intra_l, off);
    inter_l += __shfl_down(inter_l, off);
  }
  if (lane == 0) { redI[wid] = intra_l; redE[wid] = inter_l; }
  __syncthreads();
  if (tid == 0) {
    float si = 0.f, se = 0.f;
    #pragma unroll
    for (int w = 0; w < 8; ++w) { si += redI[w]; se += redE[w]; }
    atomicAdd(&accum[0], si);
    atomicAdd(&accum[1], se);
  }
}

// ---------------- mask counts + finalize (fused) ----------------
__global__ void finalize_kernel(const float* __restrict__ counts,
                                const float* __restrict__ psum,
                                const float* __restrict__ accum,
                                float* __restrict__ out) {
  int tid = threadIdx.x;
  int ni = 0, nj = 0, nd = 0;
  for (int i = tid; i < NC; i += 256) {
    int mi = counts[i] > 0.f;
    int mj = psum[i] != 0.f;
    ni += mi; nj += mj; nd += (mi & mj);
  }
  #pragma unroll
  for (int off = 32; off; off >>= 1) {
    ni += __shfl_down(ni, off);
    nj += __shfl_down(nj, off);
    nd += __shfl_down(nd, off);
  }
  __shared__ int r0[4], r1[4], r2[4];
  int wid = tid >> 6, lane = tid & 63;
  if (lane == 0) { r0[wid] = ni; r1[wid] = nj; r2[wid] = nd; }
  __syncthreads();
  if (tid == 0) {
    float fni = (float)(r0[0] + r0[1] + r0[2] + r0[3]);
    float fnj = (float)(r1[0] + r1[1] + r1[2] + r1[3]);
    float fnd = (float)(r2[0] + r2[1] + r2[2] + r2[3]);
    out[0] = accum[0] / (fnd + EPSF);
    out[1] = accum[1] / (fni * fnj - fnd + EPSF);
  }
}

extern "C" void kernel_launch(void* const* d_in, const int* in_sizes, int n_in,
                              void* d_out, int out_size, void* d_ws, size_t ws_size,
                              hipStream_t stream) {
  const float* F = (const float*)d_in[0];
  const float* P = (const float*)d_in[1];
  const int* ann = (const int*)d_in[2];
  int n_ann = in_sizes[2] / 5;

  char* ws = (char*)d_ws;
  unsigned char* Fb = (unsigned char*)ws;                          // 4 MB
  unsigned char* Pb = (unsigned char*)(ws + (size_t)NC * ND);      // 4 MB
  float* f2     = (float*)(ws + (size_t)NC * ND * 2);
  float* p2     = f2 + NC;
  float* psum   = p2 + NC;
  float* counts = psum + NC;
  float* accum  = counts + NC;  // [0]=intra_sum [1]=inter_sum

  float* out = (float*)d_out;

  mask_kernel<<<1, 256, 0, stream>>>(ann, n_ann, counts);
  convert_kernel<<<2 * NC, 256, 0, stream>>>(F, P, Fb, Pb, f2, p2, psum);
  gemm_loss_kernel<<<(NC / 256) * (NC / 256), 512, 0, stream>>>(Fb, Pb, f2, p2, counts, psum, accum);
  finalize_kernel<<<1, 256, 0, stream>>>(counts, psum, accum, out);
}